// Round 16
// baseline (107.657 us; speedup 1.0000x reference)
//
#include <hip/hip_runtime.h>

typedef __attribute__((ext_vector_type(8))) short short8;
typedef __attribute__((ext_vector_type(8))) __bf16 bf16x8;
typedef __attribute__((ext_vector_type(4))) float f32x4;
typedef __attribute__((ext_vector_type(4))) float float4v;
typedef __attribute__((ext_vector_type(2))) unsigned uint2v;
typedef __attribute__((ext_vector_type(4))) unsigned uint4v;

#define AS1 __attribute__((address_space(1)))
#define AS3 __attribute__((address_space(3)))

#define BATCH 4
#define SEQ 1024
#define DM 1024
#define NH 16
#define DKH 64
#define MROWS (BATCH * SEQ) /* 4096 */
#define N3 (3 * DM)         /* 3072 */
#define CFHALF (12582912u)  /* 4096*3072 elements per K-half partial */
#define LOG2E 1.4426950408889634f

static __device__ __forceinline__ unsigned short f2bf(float f) {
  unsigned u = __builtin_bit_cast(unsigned, f);
  u += 0x7FFFu + ((u >> 16) & 1u);
  return (unsigned short)(u >> 16);
}
static __device__ __forceinline__ float bf2f(unsigned short h) {
  return __builtin_bit_cast(float, ((unsigned)h) << 16);
}
// HW packed f32x2 -> bf16x2 (RTNE)
static __device__ __forceinline__ unsigned cvt_pk_bf16(float lo, float hi) {
  unsigned r;
  asm("v_cvt_pk_bf16_f32 %0, %1, %2" : "=v"(r) : "v"(lo), "v"(hi));
  return r;
}
static __device__ __forceinline__ f32x4 mfma16(short8 a, short8 b, f32x4 c) {
  return __builtin_amdgcn_mfma_f32_16x16x32_bf16(
      __builtin_bit_cast(bf16x8, a), __builtin_bit_cast(bf16x8, b), c, 0, 0, 0);
}

// ---------------- fp32 -> bf16 convert (x, Wq, Wk, Wv concat, Wo) ----------------
__global__ __launch_bounds__(256) void convert_kernel(
    const float* __restrict__ x, const float* __restrict__ wq,
    const float* __restrict__ wk, const float* __restrict__ wv,
    const float* __restrict__ wo, unsigned short* __restrict__ xb,
    unsigned short* __restrict__ wqkv, unsigned short* __restrict__ wob) {
  size_t i4 = ((size_t)blockIdx.x * 256 + threadIdx.x) * 4;
  const size_t SZX = (size_t)MROWS * DM;  // 4M
  const size_t SZW = (size_t)DM * DM;     // 1M
  const float* src;
  unsigned short* dst;
  size_t off;
  if (i4 < SZX) {
    src = x; dst = xb; off = i4;
  } else if (i4 < SZX + SZW) {
    src = wq; dst = wqkv; off = i4 - SZX;
  } else if (i4 < SZX + 2 * SZW) {
    src = wk; dst = wqkv + SZW; off = i4 - SZX - SZW;
  } else if (i4 < SZX + 3 * SZW) {
    src = wv; dst = wqkv + 2 * SZW; off = i4 - SZX - 2 * SZW;
  } else {
    src = wo; dst = wob; off = i4 - SZX - 3 * SZW;
  }
  float4v v = *(const float4v*)(src + off);
  uint2v o;
  o.x = cvt_pk_bf16(v.x, v.y);
  o.y = cvt_pk_bf16(v.z, v.w);
  *(uint2v*)(dst + off) = o;
}

// ---------------- QKV GEMM, SPLIT-K (kh = blockIdx.y>>5) ----------------
// C-partial[kh][M][N] over K-half kh*512..+512. grid (24,64) = 1536 blocks ->
// 5 blocks/CU (LDS-capped) vs 3 for unsplit: occupancy fix for the
// latency-bound profile (Mfma 18%/VALU 25%/Occ 14%/HBM 15% all low).
// Partials combined in rope_tv (which reads cf anyway). Tile structure is the
// verified round-11 form (coalesced scalar epilogue).
__global__ __launch_bounds__(256) void gemm_qkv(
    const unsigned short* __restrict__ A, const unsigned short* __restrict__ B,
    unsigned short* __restrict__ C, int M, int N, int K) {
  __shared__ char sA[16384];
  __shared__ char sB[16384];
  const int tid = threadIdx.x, w = tid >> 6, lane = tid & 63;
  const int g = lane >> 4, r = lane & 15;
  const int kh = blockIdx.y >> 5;
  const int m0 = (blockIdx.y & 31) * 128, n0 = blockIdx.x * 128;
  const int wm = (w >> 1) * 64, wn = (w & 1) * 64;
  unsigned short* Cp = C + (size_t)kh * CFHALF;
  f32x4 acc[4][4] = {};
  for (int k0 = kh * 512; k0 < kh * 512 + 512; k0 += 64) {
#pragma unroll
    for (int c = 0; c < 4; ++c) {
      int p = c * 4096 + tid * 16;            // linear LDS byte pos
      int o = p ^ (((p >> 7) & 7) << 4);      // inverse-swizzled logical pos
      int row = o >> 7, colb = o & 127;
      const char* ga = (const char*)(A + (size_t)(m0 + row) * K + k0) + colb;
      const char* gb = (const char*)(B + (size_t)(n0 + row) * K + k0) + colb;
      __builtin_amdgcn_global_load_lds((const AS1 void*)ga,
                                       (AS3 void*)(sA + c * 4096 + (w << 10)), 16, 0, 0);
      __builtin_amdgcn_global_load_lds((const AS1 void*)gb,
                                       (AS3 void*)(sB + c * 4096 + (w << 10)), 16, 0, 0);
    }
    __syncthreads();
#pragma unroll
    for (int kk = 0; kk < 2; ++kk) {
      short8 af[4], bfr[4];
#pragma unroll
      for (int i = 0; i < 4; ++i) {
        int ra = wm + i * 16 + r;
        af[i] = *(const short8*)(sA + (((ra << 7) + (kk << 6) + (g << 4)) ^ ((ra & 7) << 4)));
        int rb = wn + i * 16 + r;
        bfr[i] = *(const short8*)(sB + (((rb << 7) + (kk << 6) + (g << 4)) ^ ((rb & 7) << 4)));
      }
#pragma unroll
      for (int i = 0; i < 4; ++i)
#pragma unroll
        for (int j = 0; j < 4; ++j) acc[i][j] = mfma16(af[i], bfr[j], acc[i][j]);
    }
    __syncthreads();
  }
#pragma unroll
  for (int i = 0; i < 4; ++i)
#pragma unroll
    for (int j = 0; j < 4; ++j)
#pragma unroll
      for (int jj = 0; jj < 4; ++jj) {
        int row = m0 + wm + i * 16 + g * 4 + jj;
        int col = n0 + wn + j * 16 + r;
        Cp[(size_t)row * N + col] = f2bf(acc[i][j][jj]);
      }
}

// ---------------- 128x64-tile GEMM, fp32 out (out-proj) ----------
__global__ __launch_bounds__(256) void gemm_n64(
    const unsigned short* __restrict__ A, const unsigned short* __restrict__ B,
    float* __restrict__ C, int M, int N, int K) {
  __shared__ char sA[16384];
  __shared__ char sB[8192];
  const int tid = threadIdx.x, w = tid >> 6, lane = tid & 63;
  const int g = lane >> 4, r = lane & 15;
  const int m0 = blockIdx.y * 128, n0 = blockIdx.x * 64;
  const int wm = (w >> 1) * 64, wn = (w & 1) * 32;
  f32x4 acc[4][2] = {};
  for (int k0 = 0; k0 < K; k0 += 64) {
#pragma unroll
    for (int c = 0; c < 4; ++c) {
      int p = c * 4096 + tid * 16;
      int o = p ^ (((p >> 7) & 7) << 4);
      int row = o >> 7, colb = o & 127;
      const char* ga = (const char*)(A + (size_t)(m0 + row) * K + k0) + colb;
      __builtin_amdgcn_global_load_lds((const AS1 void*)ga,
                                       (AS3 void*)(sA + c * 4096 + (w << 10)), 16, 0, 0);
      if (c < 2) {
        const char* gb = (const char*)(B + (size_t)(n0 + row) * K + k0) + colb;
        __builtin_amdgcn_global_load_lds((const AS1 void*)gb,
                                         (AS3 void*)(sB + c * 4096 + (w << 10)), 16, 0, 0);
      }
    }
    __syncthreads();
#pragma unroll
    for (int kk = 0; kk < 2; ++kk) {
      short8 af[4], bfr[2];
#pragma unroll
      for (int i = 0; i < 4; ++i) {
        int ra = wm + i * 16 + r;
        af[i] = *(const short8*)(sA + (((ra << 7) + (kk << 6) + (g << 4)) ^ ((ra & 7) << 4)));
      }
#pragma unroll
      for (int j = 0; j < 2; ++j) {
        int rb = wn + j * 16 + r;
        bfr[j] = *(const short8*)(sB + (((rb << 7) + (kk << 6) + (g << 4)) ^ ((rb & 7) << 4)));
      }
#pragma unroll
      for (int i = 0; i < 4; ++i)
#pragma unroll
        for (int j = 0; j < 2; ++j) acc[i][j] = mfma16(af[i], bfr[j], acc[i][j]);
    }
    __syncthreads();
  }
#pragma unroll
  for (int i = 0; i < 4; ++i)
#pragma unroll
    for (int j = 0; j < 2; ++j)
#pragma unroll
      for (int jj = 0; jj < 4; ++jj) {
        int row = m0 + wm + i * 16 + g * 4 + jj;
        int col = n0 + wn + j * 16 + r;
        C[(size_t)row * N + col] = acc[i][j][jj];
      }
}

// ---------------- fused RoPE(Q,K) + V-transpose, with split-K combine ----------
// Reads BOTH cf partials (cf0 + cf1) and adds before RoPE / transpose.
// Q scaled by 0.125*log2e: downstream softmax works in exp2 domain.
__global__ __launch_bounds__(256) void rope_tv(const unsigned short* __restrict__ cf,
                                               unsigned short* __restrict__ qb,
                                               unsigned short* __restrict__ kb,
                                               unsigned short* __restrict__ vt) {
  __shared__ unsigned short tile[64][72];
  const int bid = blockIdx.x;
  if (bid < 2048) {
    int i = bid * 256 + threadIdx.x;  // 512K threads: ((b*1024+s)*16+h)*8+t8
    int t8 = i & 7, h = (i >> 3) & 15, s = (i >> 7) & 1023, b = i >> 17;
    size_t base = (size_t)(b * SEQ + s) * N3 + h * DKH + t8 * 8;
    short8 q8a = *(const short8*)(cf + base);
    short8 q8b = *(const short8*)(cf + CFHALF + base);
    short8 k8a = *(const short8*)(cf + base + DM);
    short8 k8b = *(const short8*)(cf + CFHALF + base + DM);
    uint4v qo, ko;
    const float qs = 0.125f * LOG2E;
#pragma unroll
    for (int p = 0; p < 4; ++p) {
      int kidx = t8 * 4 + p;
      float freq = __expf(-(float)kidx * 0.28782313662425572f);  // 10000^(-k/32)
      float sn, cs;
      __sincosf((float)s * freq, &sn, &cs);
      float qe = bf2f((unsigned short)q8a[2 * p]) + bf2f((unsigned short)q8b[2 * p]);
      float qv = bf2f((unsigned short)q8a[2 * p + 1]) + bf2f((unsigned short)q8b[2 * p + 1]);
      float ke = bf2f((unsigned short)k8a[2 * p]) + bf2f((unsigned short)k8b[2 * p]);
      float kv = bf2f((unsigned short)k8a[2 * p + 1]) + bf2f((unsigned short)k8b[2 * p + 1]);
      qo[p] = cvt_pk_bf16((qe * cs - qv * sn) * qs, (qe * sn + qv * cs) * qs);
      ko[p] = cvt_pk_bf16(ke * cs - kv * sn, ke * sn + kv * cs);
    }
    size_t dsto = (size_t)((b * NH + h) * SEQ + s) * DKH + t8 * 8;
    *(uint4v*)(qb + dsto) = qo;
    *(uint4v*)(kb + dsto) = ko;
  } else {
    int t = bid - 2048;
    int bh = t >> 4, b = bh >> 4, h = bh & 15, s0 = (t & 15) * 64;
    int tt = threadIdx.x, row = tt >> 2, c0 = (tt & 3) * 16;
    size_t base = (size_t)(b * SEQ + s0 + row) * N3 + 2 * DM + h * DKH + c0;
    short8 v0a = *(const short8*)(cf + base);
    short8 v0b = *(const short8*)(cf + CFHALF + base);
    short8 v1a = *(const short8*)(cf + base + 8);
    short8 v1b = *(const short8*)(cf + CFHALF + base + 8);
    uint4v w0, w1;
#pragma unroll
    for (int p = 0; p < 4; ++p) {
      w0[p] = cvt_pk_bf16(
          bf2f((unsigned short)v0a[2 * p]) + bf2f((unsigned short)v0b[2 * p]),
          bf2f((unsigned short)v0a[2 * p + 1]) + bf2f((unsigned short)v0b[2 * p + 1]));
      w1[p] = cvt_pk_bf16(
          bf2f((unsigned short)v1a[2 * p]) + bf2f((unsigned short)v1b[2 * p]),
          bf2f((unsigned short)v1a[2 * p + 1]) + bf2f((unsigned short)v1b[2 * p + 1]));
    }
    *(uint4v*)&tile[row][c0] = w0;
    *(uint4v*)&tile[row][c0 + 8] = w1;
    __syncthreads();
    unsigned short* dst = vt + ((size_t)bh * DKH + row) * SEQ + s0 + c0;
    short8 o0, o1;
#pragma unroll
    for (int j = 0; j < 8; ++j) o0[j] = (short)tile[c0 + j][row];
#pragma unroll
    for (int j = 0; j < 8; ++j) o1[j] = (short)tile[c0 + 8 + j][row];
    *(short8*)dst = o0;
    *(short8*)(dst + 8) = o1;
  }
}

// ---------------- causal flash attention (v8: 8-wave paired, 1 chain/wave) -------
// grid (8, 64), 512 threads. Block bx handles q-tiles qhi=15-bx AND qlo=bx.
// Waves 0-3 own the hi tile's 16-row slices; waves 4-7 the lo tile.
__global__ __launch_bounds__(512) void attn_kernel(const unsigned short* __restrict__ qb,
                                                   const unsigned short* __restrict__ kb,
                                                   const unsigned short* __restrict__ vt,
                                                   unsigned short* __restrict__ ob) {
  __shared__ char kl[2][8192];
  __shared__ char vl[2][8192];
  __shared__ unsigned short plds[8][1024];  // per-wave P buffer
  const int bx = blockIdx.x, bh = blockIdx.y, b = bh >> 4, h = bh & 15;
  const int tid = threadIdx.x, w = tid >> 6, lane = tid & 63;
  const int g = lane >> 4, r = lane & 15;
  const float DEFER = 8.f * LOG2E;
  const int qblk = (w < 4) ? (15 - bx) : bx;  // hi tile for waves 0-3, lo for 4-7
  const int nkt = qblk + 1;                   // K-tiles this wave computes
  const int NKT = 16 - bx;                    // K-tiles the block stages (hi span)
  const unsigned short* Q = qb + (size_t)bh * SEQ * DKH;
  const char* Kp = (const char*)(kb + (size_t)bh * SEQ * DKH);
  const char* Vp = (const char*)(vt + (size_t)bh * DKH * SEQ);

  const int p0 = tid * 16;
  const int o0 = p0 ^ (((p0 >> 7) & 7) << 4);  // inverse-swizzled logical pos
  const size_t ks0 = (size_t)(o0 >> 7) * 128 + (o0 & 127);
  const size_t vs0 = (size_t)(o0 >> 7) * 2048 + (o0 & 127);

#define STAGE_KV(bi, kt)                                                          \
  do {                                                                            \
    const char* kbase = Kp + (size_t)(kt) * 8192;                                 \
    const char* vbase = Vp + (size_t)(kt) * 128;                                  \
    __builtin_amdgcn_global_load_lds((const AS1 void*)(kbase + ks0),              \
                                     (AS3 void*)(kl[bi] + p0), 16, 0, 0);         \
    __builtin_amdgcn_global_load_lds((const AS1 void*)(vbase + vs0),              \
                                     (AS3 void*)(vl[bi] + p0), 16, 0, 0);         \
  } while (0)

  short8 qf0, qf1;
  {
    int qrow = qblk * 64 + (w & 3) * 16 + r;
    qf0 = *(const short8*)(Q + (size_t)qrow * DKH + g * 8);
    qf1 = *(const short8*)(Q + (size_t)qrow * DKH + 32 + g * 8);
  }
  f32x4 oacc[4] = {};
  float mrun = -1e30f, lrun = 0.f;
  const int qg = qblk * 64 + (w & 3) * 16 + r;  // this lane's q-row (global)
  char* pbase = (char*)&plds[w][0];

  STAGE_KV(0, 0);
  __syncthreads();

  for (int kt = 0; kt < NKT; ++kt) {
    if (kt + 1 < NKT) STAGE_KV((kt + 1) & 1, kt + 1);  // prefetch next tile
    if (kt < nkt) {  // wave-uniform: lo-waves skip compute past their span
      const char* kb_ = kl[kt & 1];
      const char* vb_ = vl[kt & 1];
      f32x4 sh[4] = {};
#pragma unroll
      for (int nb = 0; nb < 4; ++nb) {
        int ra = nb * 16 + r;
        short8 kf0 = *(const short8*)(kb_ + ((ra * 128 + g * 16) ^ ((ra & 7) << 4)));
        short8 kf1 = *(const short8*)(kb_ + ((ra * 128 + 64 + g * 16) ^ ((ra & 7) << 4)));
        sh[nb] = mfma16(kf0, qf0, sh[nb]);  // swapped: S[k][q]
        sh[nb] = mfma16(kf1, qf1, sh[nb]);
      }
      if (kt == nkt - 1) {  // diagonal: mask k > q (per-lane q)
#pragma unroll
        for (int nb = 0; nb < 4; ++nb)
#pragma unroll
          for (int j = 0; j < 4; ++j)
            if (kt * 64 + nb * 16 + g * 4 + j > qg) sh[nb][j] = -1e30f;
      }
      // ---- per-lane softmax (defer-max, exp2 domain) ----
      {
        float a0 = fmaxf(fmaxf(sh[0][0], sh[0][1]), fmaxf(sh[0][2], sh[0][3]));
        float a1 = fmaxf(fmaxf(sh[1][0], sh[1][1]), fmaxf(sh[1][2], sh[1][3]));
        float a2 = fmaxf(fmaxf(sh[2][0], sh[2][1]), fmaxf(sh[2][2], sh[2][3]));
        float a3 = fmaxf(fmaxf(sh[3][0], sh[3][1]), fmaxf(sh[3][2], sh[3][3]));
        float tm = fmaxf(fmaxf(a0, a1), fmaxf(a2, a3));
        tm = fmaxf(tm, __shfl_xor(tm, 16, 64));
        tm = fmaxf(tm, __shfl_xor(tm, 32, 64));
        if (!__all(tm <= mrun + DEFER)) {
          float mnew = fmaxf(mrun, tm);
          float scl = exp2f(mrun - mnew);
          mrun = mnew;
          lrun *= scl;
#pragma unroll
          for (int db = 0; db < 4; ++db) {
            f32x4 t = oacc[db];
            t[0] *= scl; t[1] *= scl; t[2] *= scl; t[3] *= scl;
            oacc[db] = t;
          }
        }
        float ps = 0.f;
#pragma unroll
        for (int nb = 0; nb < 4; ++nb)
#pragma unroll
          for (int j = 0; j < 4; ++j) {
            float p = exp2f(sh[nb][j] - mrun);
            sh[nb][j] = p;
            ps += p;
          }
        ps += __shfl_xor(ps, 16, 64);
        ps += __shfl_xor(ps, 32, 64);
        lrun += ps;
#pragma unroll
        for (int nb = 0; nb < 4; ++nb) {
          uint2v pk;
          pk.x = cvt_pk_bf16(sh[nb][0], sh[nb][1]);
          pk.y = cvt_pk_bf16(sh[nb][2], sh[nb][3]);
          *(uint2v*)(pbase + ((r * 128 + nb * 32 + g * 8) ^ ((r & 7) << 4))) = pk;
        }
      }
      // P write -> read is same-wave only
      asm volatile("s_waitcnt lgkmcnt(0)" ::: "memory");
      __builtin_amdgcn_sched_barrier(0);
      short8 pf0 = *(const short8*)(pbase + ((r * 128 + g * 16) ^ ((r & 7) << 4)));
      short8 pf1 = *(const short8*)(pbase + ((r * 128 + 64 + g * 16) ^ ((r & 7) << 4)));
#pragma unroll
      for (int db = 0; db < 4; ++db) {
        int rv = db * 16 + r;
        short8 vf0 = *(const short8*)(vb_ + ((rv * 128 + g * 16) ^ ((rv & 7) << 4)));
        short8 vf1 = *(const short8*)(vb_ + ((rv * 128 + 64 + g * 16) ^ ((rv & 7) << 4)));
        oacc[db] = mfma16(vf0, pf0, oacc[db]);  // swapped: O[d][q]
        oacc[db] = mfma16(vf1, pf1, oacc[db]);
      }
    }
    __syncthreads();  // staging drained + all waves done with buffers
  }
  // epilogue: lane holds O[d=db*16+g*4+j][q=own row]; pack 4 bf16 -> 8B stores
  {
    float inv = 1.f / lrun;
    unsigned short* orow = ob + (size_t)(b * SEQ + qg) * DM + h * DKH;
#pragma unroll
    for (int db = 0; db < 4; ++db) {
      uint2v pk;
      pk.x = cvt_pk_bf16(oacc[db][0] * inv, oacc[db][1] * inv);
      pk.y = cvt_pk_bf16(oacc[db][2] * inv, oacc[db][3] * inv);
      *(uint2v*)(orow + db * 16 + g * 4) = pk;
    }
  }
#undef STAGE_KV
}

extern "C" void kernel_launch(void* const* d_in, const int* in_sizes, int n_in,
                              void* d_out, int out_size, void* d_ws, size_t ws_size,
                              hipStream_t stream) {
  const float* x = (const float*)d_in[0];
  // d_in[1] = token_positions (reference ignores it; positions == arange(S))
  const float* wq = (const float*)d_in[2];
  const float* wk = (const float*)d_in[3];
  const float* wv = (const float*)d_in[4];
  const float* wo = (const float*)d_in[5];
  char* ws = (char*)d_ws;
  unsigned short* xb = (unsigned short*)(ws);                  // 8 MiB
  unsigned short* wqkv = (unsigned short*)(ws + (8u << 20));   // 6 MiB [Wq;Wk;Wv][3072][1024]
  unsigned short* wob = (unsigned short*)(ws + (14u << 20));   // 2 MiB
  unsigned short* cf = (unsigned short*)(ws + (16u << 20));    // 48 MiB: cf0 + cf1 partials
  unsigned short* qbuf = (unsigned short*)(ws + (64u << 20));  // 8 MiB (bh,s,d)
  unsigned short* kbuf = (unsigned short*)(ws + (72u << 20));  // 8 MiB (bh,s,d)
  unsigned short* vtb = (unsigned short*)(ws + (80u << 20));   // 8 MiB (bh,d,s)
  unsigned short* obuf = (unsigned short*)(ws + (88u << 20));  // 8 MiB (b,s,e)
  float* out = (float*)d_out;

  convert_kernel<<<8192, 256, 0, stream>>>(x, wq, wk, wv, wo, xb, wqkv, wob);
  gemm_qkv<<<dim3(24, 64), 256, 0, stream>>>(xb, wqkv, cf, MROWS, N3, DM);
  rope_tv<<<3072, 256, 0, stream>>>(cf, qbuf, kbuf, vtb);
  attn_kernel<<<dim3(8, 64), 512, 0, stream>>>(qbuf, kbuf, vtb, obuf);
  gemm_n64<<<dim3(16, 32), 256, 0, stream>>>(obuf, wob, out, MROWS, DM, DM);
}

// Round 17
// 107.623 us; speedup vs baseline: 1.0003x; 1.0003x over previous
//
#include <hip/hip_runtime.h>

typedef __attribute__((ext_vector_type(8))) short short8;
typedef __attribute__((ext_vector_type(8))) __bf16 bf16x8;
typedef __attribute__((ext_vector_type(4))) float f32x4;
typedef __attribute__((ext_vector_type(4))) float float4v;
typedef __attribute__((ext_vector_type(2))) unsigned uint2v;
typedef __attribute__((ext_vector_type(4))) unsigned uint4v;

#define AS1 __attribute__((address_space(1)))
#define AS3 __attribute__((address_space(3)))

#define BATCH 4
#define SEQ 1024
#define DM 1024
#define NH 16
#define DKH 64
#define MROWS (BATCH * SEQ) /* 4096 */
#define N3 (3 * DM)         /* 3072 */
#define LOG2E 1.4426950408889634f

static __device__ __forceinline__ unsigned short f2bf(float f) {
  unsigned u = __builtin_bit_cast(unsigned, f);
  u += 0x7FFFu + ((u >> 16) & 1u);
  return (unsigned short)(u >> 16);
}
static __device__ __forceinline__ float bf2f(unsigned short h) {
  return __builtin_bit_cast(float, ((unsigned)h) << 16);
}
// HW packed f32x2 -> bf16x2 (RTNE)
static __device__ __forceinline__ unsigned cvt_pk_bf16(float lo, float hi) {
  unsigned r;
  asm("v_cvt_pk_bf16_f32 %0, %1, %2" : "=v"(r) : "v"(lo), "v"(hi));
  return r;
}
static __device__ __forceinline__ f32x4 mfma16(short8 a, short8 b, f32x4 c) {
  return __builtin_amdgcn_mfma_f32_16x16x32_bf16(
      __builtin_bit_cast(bf16x8, a), __builtin_bit_cast(bf16x8, b), c, 0, 0, 0);
}

// ---------------- fp32 -> bf16 convert (x, Wq, Wk, Wv concat, Wo) ----------------
__global__ __launch_bounds__(256) void convert_kernel(
    const float* __restrict__ x, const float* __restrict__ wq,
    const float* __restrict__ wk, const float* __restrict__ wv,
    const float* __restrict__ wo, unsigned short* __restrict__ xb,
    unsigned short* __restrict__ wqkv, unsigned short* __restrict__ wob) {
  size_t i4 = ((size_t)blockIdx.x * 256 + threadIdx.x) * 4;
  const size_t SZX = (size_t)MROWS * DM;  // 4M
  const size_t SZW = (size_t)DM * DM;     // 1M
  const float* src;
  unsigned short* dst;
  size_t off;
  if (i4 < SZX) {
    src = x; dst = xb; off = i4;
  } else if (i4 < SZX + SZW) {
    src = wq; dst = wqkv; off = i4 - SZX;
  } else if (i4 < SZX + 2 * SZW) {
    src = wk; dst = wqkv + SZW; off = i4 - SZX - SZW;
  } else if (i4 < SZX + 3 * SZW) {
    src = wv; dst = wqkv + 2 * SZW; off = i4 - SZX - 2 * SZW;
  } else {
    src = wo; dst = wob; off = i4 - SZX - 3 * SZW;
  }
  float4v v = *(const float4v*)(src + off);
  uint2v o;
  o.x = cvt_pk_bf16(v.x, v.y);
  o.y = cvt_pk_bf16(v.z, v.w);
  *(uint2v*)(dst + off) = o;
}

// ---------------- 128x64-tile GEMM: C[M][N] = A[M][K]*B[N][K]^T ----------------
// 4 waves as 2x2 of 64x32; LDS 24KB -> 6 blocks/CU at grid (N/64, M/128).
// Used for BOTH the QKV GEMM (bf16 out, grid 48x32 = 6 blocks/CU -- the
// occupancy fix for the latency-bound 128x128 version, with ZERO extra
// traffic, r16 lesson: split-K's partial write+read cost > occupancy gain)
// and the out-proj (f32 out, grid 16x32).
static __device__ __forceinline__ void store_c(float* p, float v) { *p = v; }
static __device__ __forceinline__ void store_c(unsigned short* p, float v) { *p = f2bf(v); }

template <typename OutT>
__global__ __launch_bounds__(256) void gemm_n64(
    const unsigned short* __restrict__ A, const unsigned short* __restrict__ B,
    OutT* __restrict__ C, int M, int N, int K) {
  __shared__ char sA[16384];
  __shared__ char sB[8192];
  const int tid = threadIdx.x, w = tid >> 6, lane = tid & 63;
  const int g = lane >> 4, r = lane & 15;
  const int m0 = blockIdx.y * 128, n0 = blockIdx.x * 64;
  const int wm = (w >> 1) * 64, wn = (w & 1) * 32;
  f32x4 acc[4][2] = {};
  for (int k0 = 0; k0 < K; k0 += 64) {
#pragma unroll
    for (int c = 0; c < 4; ++c) {
      int p = c * 4096 + tid * 16;
      int o = p ^ (((p >> 7) & 7) << 4);
      int row = o >> 7, colb = o & 127;
      const char* ga = (const char*)(A + (size_t)(m0 + row) * K + k0) + colb;
      __builtin_amdgcn_global_load_lds((const AS1 void*)ga,
                                       (AS3 void*)(sA + c * 4096 + (w << 10)), 16, 0, 0);
      if (c < 2) {
        const char* gb = (const char*)(B + (size_t)(n0 + row) * K + k0) + colb;
        __builtin_amdgcn_global_load_lds((const AS1 void*)gb,
                                         (AS3 void*)(sB + c * 4096 + (w << 10)), 16, 0, 0);
      }
    }
    __syncthreads();
#pragma unroll
    for (int kk = 0; kk < 2; ++kk) {
      short8 af[4], bfr[2];
#pragma unroll
      for (int i = 0; i < 4; ++i) {
        int ra = wm + i * 16 + r;
        af[i] = *(const short8*)(sA + (((ra << 7) + (kk << 6) + (g << 4)) ^ ((ra & 7) << 4)));
      }
#pragma unroll
      for (int j = 0; j < 2; ++j) {
        int rb = wn + j * 16 + r;
        bfr[j] = *(const short8*)(sB + (((rb << 7) + (kk << 6) + (g << 4)) ^ ((rb & 7) << 4)));
      }
#pragma unroll
      for (int i = 0; i < 4; ++i)
#pragma unroll
        for (int j = 0; j < 2; ++j) acc[i][j] = mfma16(af[i], bfr[j], acc[i][j]);
    }
    __syncthreads();
  }
#pragma unroll
  for (int i = 0; i < 4; ++i)
#pragma unroll
    for (int j = 0; j < 2; ++j)
#pragma unroll
      for (int jj = 0; jj < 4; ++jj) {
        int row = m0 + wm + i * 16 + g * 4 + jj;
        int col = n0 + wn + j * 16 + r;
        store_c(&C[(size_t)row * N + col], acc[i][j][jj]);
      }
}

// ---------------- fused RoPE(Q,K) (vectorized) + V-transpose ----------------
// Q scaled by 0.125*log2e: downstream softmax works in exp2 domain.
__global__ __launch_bounds__(256) void rope_tv(const unsigned short* __restrict__ cf,
                                               unsigned short* __restrict__ qb,
                                               unsigned short* __restrict__ kb,
                                               unsigned short* __restrict__ vt) {
  __shared__ unsigned short tile[64][72];
  const int bid = blockIdx.x;
  if (bid < 2048) {
    int i = bid * 256 + threadIdx.x;  // 512K threads: ((b*1024+s)*16+h)*8+t8
    int t8 = i & 7, h = (i >> 3) & 15, s = (i >> 7) & 1023, b = i >> 17;
    const unsigned short* src = cf + (size_t)(b * SEQ + s) * N3 + h * DKH + t8 * 8;
    short8 q8 = *(const short8*)src;
    short8 k8 = *(const short8*)(src + DM);
    uint4v qo, ko;
    const float qs = 0.125f * LOG2E;
#pragma unroll
    for (int p = 0; p < 4; ++p) {
      int kidx = t8 * 4 + p;
      float freq = __expf(-(float)kidx * 0.28782313662425572f);  // 10000^(-k/32)
      float sn, cs;
      __sincosf((float)s * freq, &sn, &cs);
      float qe = bf2f((unsigned short)q8[2 * p]), qv = bf2f((unsigned short)q8[2 * p + 1]);
      float ke = bf2f((unsigned short)k8[2 * p]), kv = bf2f((unsigned short)k8[2 * p + 1]);
      qo[p] = cvt_pk_bf16((qe * cs - qv * sn) * qs, (qe * sn + qv * cs) * qs);
      ko[p] = cvt_pk_bf16(ke * cs - kv * sn, ke * sn + kv * cs);
    }
    size_t dsto = (size_t)((b * NH + h) * SEQ + s) * DKH + t8 * 8;
    *(uint4v*)(qb + dsto) = qo;
    *(uint4v*)(kb + dsto) = ko;
  } else {
    int t = bid - 2048;
    int bh = t >> 4, b = bh >> 4, h = bh & 15, s0 = (t & 15) * 64;
    int tt = threadIdx.x, row = tt >> 2, c0 = (tt & 3) * 16;
    const unsigned short* src = cf + (size_t)(b * SEQ + s0 + row) * N3 + 2 * DM + h * DKH + c0;
    short8 v0 = *(const short8*)src;
    short8 v1 = *(const short8*)(src + 8);
    *(short8*)&tile[row][c0] = v0;
    *(short8*)&tile[row][c0 + 8] = v1;
    __syncthreads();
    unsigned short* dst = vt + ((size_t)bh * DKH + row) * SEQ + s0 + c0;
    short8 o0, o1;
#pragma unroll
    for (int j = 0; j < 8; ++j) o0[j] = (short)tile[c0 + j][row];
#pragma unroll
    for (int j = 0; j < 8; ++j) o1[j] = (short)tile[c0 + 8 + j][row];
    *(short8*)dst = o0;
    *(short8*)(dst + 8) = o1;
  }
}

// ---------------- causal flash attention (v8: 8-wave paired, 1 chain/wave) -------
// grid (8, 64), 512 threads. Block bx handles q-tiles qhi=15-bx AND qlo=bx.
// Waves 0-3 own the hi tile's 16-row slices; waves 4-7 the lo tile.
__global__ __launch_bounds__(512) void attn_kernel(const unsigned short* __restrict__ qb,
                                                   const unsigned short* __restrict__ kb,
                                                   const unsigned short* __restrict__ vt,
                                                   unsigned short* __restrict__ ob) {
  __shared__ char kl[2][8192];
  __shared__ char vl[2][8192];
  __shared__ unsigned short plds[8][1024];  // per-wave P buffer
  const int bx = blockIdx.x, bh = blockIdx.y, b = bh >> 4, h = bh & 15;
  const int tid = threadIdx.x, w = tid >> 6, lane = tid & 63;
  const int g = lane >> 4, r = lane & 15;
  const float DEFER = 8.f * LOG2E;
  const int qblk = (w < 4) ? (15 - bx) : bx;  // hi tile for waves 0-3, lo for 4-7
  const int nkt = qblk + 1;                   // K-tiles this wave computes
  const int NKT = 16 - bx;                    // K-tiles the block stages (hi span)
  const unsigned short* Q = qb + (size_t)bh * SEQ * DKH;
  const char* Kp = (const char*)(kb + (size_t)bh * SEQ * DKH);
  const char* Vp = (const char*)(vt + (size_t)bh * DKH * SEQ);

  const int p0 = tid * 16;
  const int o0 = p0 ^ (((p0 >> 7) & 7) << 4);  // inverse-swizzled logical pos
  const size_t ks0 = (size_t)(o0 >> 7) * 128 + (o0 & 127);
  const size_t vs0 = (size_t)(o0 >> 7) * 2048 + (o0 & 127);

#define STAGE_KV(bi, kt)                                                          \
  do {                                                                            \
    const char* kbase = Kp + (size_t)(kt) * 8192;                                 \
    const char* vbase = Vp + (size_t)(kt) * 128;                                  \
    __builtin_amdgcn_global_load_lds((const AS1 void*)(kbase + ks0),              \
                                     (AS3 void*)(kl[bi] + p0), 16, 0, 0);         \
    __builtin_amdgcn_global_load_lds((const AS1 void*)(vbase + vs0),              \
                                     (AS3 void*)(vl[bi] + p0), 16, 0, 0);         \
  } while (0)

  short8 qf0, qf1;
  {
    int qrow = qblk * 64 + (w & 3) * 16 + r;
    qf0 = *(const short8*)(Q + (size_t)qrow * DKH + g * 8);
    qf1 = *(const short8*)(Q + (size_t)qrow * DKH + 32 + g * 8);
  }
  f32x4 oacc[4] = {};
  float mrun = -1e30f, lrun = 0.f;
  const int qg = qblk * 64 + (w & 3) * 16 + r;  // this lane's q-row (global)
  char* pbase = (char*)&plds[w][0];

  STAGE_KV(0, 0);
  __syncthreads();

  for (int kt = 0; kt < NKT; ++kt) {
    if (kt + 1 < NKT) STAGE_KV((kt + 1) & 1, kt + 1);  // prefetch next tile
    if (kt < nkt) {  // wave-uniform: lo-waves skip compute past their span
      const char* kb_ = kl[kt & 1];
      const char* vb_ = vl[kt & 1];
      f32x4 sh[4] = {};
#pragma unroll
      for (int nb = 0; nb < 4; ++nb) {
        int ra = nb * 16 + r;
        short8 kf0 = *(const short8*)(kb_ + ((ra * 128 + g * 16) ^ ((ra & 7) << 4)));
        short8 kf1 = *(const short8*)(kb_ + ((ra * 128 + 64 + g * 16) ^ ((ra & 7) << 4)));
        sh[nb] = mfma16(kf0, qf0, sh[nb]);  // swapped: S[k][q]
        sh[nb] = mfma16(kf1, qf1, sh[nb]);
      }
      if (kt == nkt - 1) {  // diagonal: mask k > q (per-lane q)
#pragma unroll
        for (int nb = 0; nb < 4; ++nb)
#pragma unroll
          for (int j = 0; j < 4; ++j)
            if (kt * 64 + nb * 16 + g * 4 + j > qg) sh[nb][j] = -1e30f;
      }
      // ---- per-lane softmax (defer-max, exp2 domain) ----
      {
        float a0 = fmaxf(fmaxf(sh[0][0], sh[0][1]), fmaxf(sh[0][2], sh[0][3]));
        float a1 = fmaxf(fmaxf(sh[1][0], sh[1][1]), fmaxf(sh[1][2], sh[1][3]));
        float a2 = fmaxf(fmaxf(sh[2][0], sh[2][1]), fmaxf(sh[2][2], sh[2][3]));
        float a3 = fmaxf(fmaxf(sh[3][0], sh[3][1]), fmaxf(sh[3][2], sh[3][3]));
        float tm = fmaxf(fmaxf(a0, a1), fmaxf(a2, a3));
        tm = fmaxf(tm, __shfl_xor(tm, 16, 64));
        tm = fmaxf(tm, __shfl_xor(tm, 32, 64));
        if (!__all(tm <= mrun + DEFER)) {
          float mnew = fmaxf(mrun, tm);
          float scl = exp2f(mrun - mnew);
          mrun = mnew;
          lrun *= scl;
#pragma unroll
          for (int db = 0; db < 4; ++db) {
            f32x4 t = oacc[db];
            t[0] *= scl; t[1] *= scl; t[2] *= scl; t[3] *= scl;
            oacc[db] = t;
          }
        }
        float ps = 0.f;
#pragma unroll
        for (int nb = 0; nb < 4; ++nb)
#pragma unroll
          for (int j = 0; j < 4; ++j) {
            float p = exp2f(sh[nb][j] - mrun);
            sh[nb][j] = p;
            ps += p;
          }
        ps += __shfl_xor(ps, 16, 64);
        ps += __shfl_xor(ps, 32, 64);
        lrun += ps;
#pragma unroll
        for (int nb = 0; nb < 4; ++nb) {
          uint2v pk;
          pk.x = cvt_pk_bf16(sh[nb][0], sh[nb][1]);
          pk.y = cvt_pk_bf16(sh[nb][2], sh[nb][3]);
          *(uint2v*)(pbase + ((r * 128 + nb * 32 + g * 8) ^ ((r & 7) << 4))) = pk;
        }
      }
      // P write -> read is same-wave only
      asm volatile("s_waitcnt lgkmcnt(0)" ::: "memory");
      __builtin_amdgcn_sched_barrier(0);
      short8 pf0 = *(const short8*)(pbase + ((r * 128 + g * 16) ^ ((r & 7) << 4)));
      short8 pf1 = *(const short8*)(pbase + ((r * 128 + 64 + g * 16) ^ ((r & 7) << 4)));
#pragma unroll
      for (int db = 0; db < 4; ++db) {
        int rv = db * 16 + r;
        short8 vf0 = *(const short8*)(vb_ + ((rv * 128 + g * 16) ^ ((rv & 7) << 4)));
        short8 vf1 = *(const short8*)(vb_ + ((rv * 128 + 64 + g * 16) ^ ((rv & 7) << 4)));
        oacc[db] = mfma16(vf0, pf0, oacc[db]);  // swapped: O[d][q]
        oacc[db] = mfma16(vf1, pf1, oacc[db]);
      }
    }
    __syncthreads();  // staging drained + all waves done with buffers
  }
  // epilogue: lane holds O[d=db*16+g*4+j][q=own row]; pack 4 bf16 -> 8B stores
  {
    float inv = 1.f / lrun;
    unsigned short* orow = ob + (size_t)(b * SEQ + qg) * DM + h * DKH;
#pragma unroll
    for (int db = 0; db < 4; ++db) {
      uint2v pk;
      pk.x = cvt_pk_bf16(oacc[db][0] * inv, oacc[db][1] * inv);
      pk.y = cvt_pk_bf16(oacc[db][2] * inv, oacc[db][3] * inv);
      *(uint2v*)(orow + db * 16 + g * 4) = pk;
    }
  }
#undef STAGE_KV
}

extern "C" void kernel_launch(void* const* d_in, const int* in_sizes, int n_in,
                              void* d_out, int out_size, void* d_ws, size_t ws_size,
                              hipStream_t stream) {
  const float* x = (const float*)d_in[0];
  // d_in[1] = token_positions (reference ignores it; positions == arange(S))
  const float* wq = (const float*)d_in[2];
  const float* wk = (const float*)d_in[3];
  const float* wv = (const float*)d_in[4];
  const float* wo = (const float*)d_in[5];
  char* ws = (char*)d_ws;
  unsigned short* xb = (unsigned short*)(ws);                  // 8 MiB
  unsigned short* wqkv = (unsigned short*)(ws + (8u << 20));   // 6 MiB [Wq;Wk;Wv][3072][1024]
  unsigned short* wob = (unsigned short*)(ws + (14u << 20));   // 2 MiB
  unsigned short* cf = (unsigned short*)(ws + (16u << 20));    // 24 MiB QKV gemm out (b,s,3072)
  unsigned short* qbuf = (unsigned short*)(ws + (40u << 20));  // 8 MiB (bh,s,d)
  unsigned short* kbuf = (unsigned short*)(ws + (48u << 20));  // 8 MiB (bh,s,d)
  unsigned short* vtb = (unsigned short*)(ws + (56u << 20));   // 8 MiB (bh,d,s)
  unsigned short* obuf = (unsigned short*)(ws + (64u << 20));  // 8 MiB (b,s,e)
  float* out = (float*)d_out;

  convert_kernel<<<8192, 256, 0, stream>>>(x, wq, wk, wv, wo, xb, wqkv, wob);
  gemm_n64<unsigned short><<<dim3(48, 32), 256, 0, stream>>>(xb, wqkv, cf, MROWS, N3, DM);
  rope_tv<<<3072, 256, 0, stream>>>(cf, qbuf, kbuf, vtb);
  attn_kernel<<<dim3(8, 64), 512, 0, stream>>>(qbuf, kbuf, vtb, obuf);
  gemm_n64<float><<<dim3(16, 32), 256, 0, stream>>>(obuf, wob, out, MROWS, DM, DM);
}

// Round 18
// 101.873 us; speedup vs baseline: 1.0568x; 1.0564x over previous
//
#include <hip/hip_runtime.h>

typedef __attribute__((ext_vector_type(8))) short short8;
typedef __attribute__((ext_vector_type(8))) __bf16 bf16x8;
typedef __attribute__((ext_vector_type(4))) float f32x4;
typedef __attribute__((ext_vector_type(4))) float float4v;
typedef __attribute__((ext_vector_type(2))) unsigned uint2v;
typedef __attribute__((ext_vector_type(4))) unsigned uint4v;

#define AS1 __attribute__((address_space(1)))
#define AS3 __attribute__((address_space(3)))

#define BATCH 4
#define SEQ 1024
#define DM 1024
#define NH 16
#define DKH 64
#define MROWS (BATCH * SEQ) /* 4096 */
#define N3 (3 * DM)         /* 3072 */
#define LOG2E 1.4426950408889634f

static __device__ __forceinline__ unsigned short f2bf(float f) {
  unsigned u = __builtin_bit_cast(unsigned, f);
  u += 0x7FFFu + ((u >> 16) & 1u);
  return (unsigned short)(u >> 16);
}
static __device__ __forceinline__ float bf2f(unsigned short h) {
  return __builtin_bit_cast(float, ((unsigned)h) << 16);
}
// HW packed f32x2 -> bf16x2 (RTNE)
static __device__ __forceinline__ unsigned cvt_pk_bf16(float lo, float hi) {
  unsigned r;
  asm("v_cvt_pk_bf16_f32 %0, %1, %2" : "=v"(r) : "v"(lo), "v"(hi));
  return r;
}
static __device__ __forceinline__ f32x4 mfma16(short8 a, short8 b, f32x4 c) {
  return __builtin_amdgcn_mfma_f32_16x16x32_bf16(
      __builtin_bit_cast(bf16x8, a), __builtin_bit_cast(bf16x8, b), c, 0, 0, 0);
}

// ---------------- fp32 -> bf16 convert (x, Wq, Wk, Wv concat, Wo) ----------------
__global__ __launch_bounds__(256) void convert_kernel(
    const float* __restrict__ x, const float* __restrict__ wq,
    const float* __restrict__ wk, const float* __restrict__ wv,
    const float* __restrict__ wo, unsigned short* __restrict__ xb,
    unsigned short* __restrict__ wqkv, unsigned short* __restrict__ wob) {
  size_t i4 = ((size_t)blockIdx.x * 256 + threadIdx.x) * 4;
  const size_t SZX = (size_t)MROWS * DM;  // 4M
  const size_t SZW = (size_t)DM * DM;     // 1M
  const float* src;
  unsigned short* dst;
  size_t off;
  if (i4 < SZX) {
    src = x; dst = xb; off = i4;
  } else if (i4 < SZX + SZW) {
    src = wq; dst = wqkv; off = i4 - SZX;
  } else if (i4 < SZX + 2 * SZW) {
    src = wk; dst = wqkv + SZW; off = i4 - SZX - SZW;
  } else if (i4 < SZX + 3 * SZW) {
    src = wv; dst = wqkv + 2 * SZW; off = i4 - SZX - 2 * SZW;
  } else {
    src = wo; dst = wob; off = i4 - SZX - 3 * SZW;
  }
  float4v v = *(const float4v*)(src + off);
  uint2v o;
  o.x = cvt_pk_bf16(v.x, v.y);
  o.y = cvt_pk_bf16(v.z, v.w);
  *(uint2v*)(dst + off) = o;
}

// ---------------- bf16 GEMM: C[M][N] = A[M][K] * B[N][K]^T (round-11 form) ------
// 128x128 tile, BK=64, 4 waves (2x2 of 64x64), global_load_lds + XOR swizzle.
// Epilogue: scalar stores, lane r walks contiguous columns (coalesced 32B runs).
// r16/r17 lessons: split-K (+48MB traffic) and 128x64 tile (lower compute
// density) both LOSE to this shape despite higher occupancy -- this is the
// 2-barrier structure's ceiling for K=1024; keep as-is.
static __device__ __forceinline__ void store_c(float* p, float v) { *p = v; }
static __device__ __forceinline__ void store_c(unsigned short* p, float v) { *p = f2bf(v); }

template <typename OutT>
__global__ __launch_bounds__(256) void gemm_bt(
    const unsigned short* __restrict__ A, const unsigned short* __restrict__ B,
    OutT* __restrict__ C, int M, int N, int K) {
  __shared__ char sA[16384];
  __shared__ char sB[16384];
  const int tid = threadIdx.x, w = tid >> 6, lane = tid & 63;
  const int g = lane >> 4, r = lane & 15;
  const int m0 = blockIdx.y * 128, n0 = blockIdx.x * 128;
  const int wm = (w >> 1) * 64, wn = (w & 1) * 64;
  f32x4 acc[4][4] = {};
  for (int k0 = 0; k0 < K; k0 += 64) {
#pragma unroll
    for (int c = 0; c < 4; ++c) {
      int p = c * 4096 + tid * 16;            // linear LDS byte pos
      int o = p ^ (((p >> 7) & 7) << 4);      // inverse-swizzled logical pos
      int row = o >> 7, colb = o & 127;
      const char* ga = (const char*)(A + (size_t)(m0 + row) * K + k0) + colb;
      const char* gb = (const char*)(B + (size_t)(n0 + row) * K + k0) + colb;
      __builtin_amdgcn_global_load_lds((const AS1 void*)ga,
                                       (AS3 void*)(sA + c * 4096 + (w << 10)), 16, 0, 0);
      __builtin_amdgcn_global_load_lds((const AS1 void*)gb,
                                       (AS3 void*)(sB + c * 4096 + (w << 10)), 16, 0, 0);
    }
    __syncthreads();
#pragma unroll
    for (int kk = 0; kk < 2; ++kk) {
      short8 af[4], bfr[4];
#pragma unroll
      for (int i = 0; i < 4; ++i) {
        int ra = wm + i * 16 + r;
        af[i] = *(const short8*)(sA + (((ra << 7) + (kk << 6) + (g << 4)) ^ ((ra & 7) << 4)));
        int rb = wn + i * 16 + r;
        bfr[i] = *(const short8*)(sB + (((rb << 7) + (kk << 6) + (g << 4)) ^ ((rb & 7) << 4)));
      }
#pragma unroll
      for (int i = 0; i < 4; ++i)
#pragma unroll
        for (int j = 0; j < 4; ++j) acc[i][j] = mfma16(af[i], bfr[j], acc[i][j]);
    }
    __syncthreads();
  }
#pragma unroll
  for (int i = 0; i < 4; ++i)
#pragma unroll
    for (int j = 0; j < 4; ++j)
#pragma unroll
      for (int jj = 0; jj < 4; ++jj) {
        int row = m0 + wm + i * 16 + g * 4 + jj;
        int col = n0 + wn + j * 16 + r;
        store_c(&C[(size_t)row * N + col], acc[i][j][jj]);
      }
}

// ---------------- 128x64-tile GEMM, fp32 out (out-proj) ----------
__global__ __launch_bounds__(256) void gemm_n64(
    const unsigned short* __restrict__ A, const unsigned short* __restrict__ B,
    float* __restrict__ C, int M, int N, int K) {
  __shared__ char sA[16384];
  __shared__ char sB[8192];
  const int tid = threadIdx.x, w = tid >> 6, lane = tid & 63;
  const int g = lane >> 4, r = lane & 15;
  const int m0 = blockIdx.y * 128, n0 = blockIdx.x * 64;
  const int wm = (w >> 1) * 64, wn = (w & 1) * 32;
  f32x4 acc[4][2] = {};
  for (int k0 = 0; k0 < K; k0 += 64) {
#pragma unroll
    for (int c = 0; c < 4; ++c) {
      int p = c * 4096 + tid * 16;
      int o = p ^ (((p >> 7) & 7) << 4);
      int row = o >> 7, colb = o & 127;
      const char* ga = (const char*)(A + (size_t)(m0 + row) * K + k0) + colb;
      __builtin_amdgcn_global_load_lds((const AS1 void*)ga,
                                       (AS3 void*)(sA + c * 4096 + (w << 10)), 16, 0, 0);
      if (c < 2) {
        const char* gb = (const char*)(B + (size_t)(n0 + row) * K + k0) + colb;
        __builtin_amdgcn_global_load_lds((const AS1 void*)gb,
                                         (AS3 void*)(sB + c * 4096 + (w << 10)), 16, 0, 0);
      }
    }
    __syncthreads();
#pragma unroll
    for (int kk = 0; kk < 2; ++kk) {
      short8 af[4], bfr[2];
#pragma unroll
      for (int i = 0; i < 4; ++i) {
        int ra = wm + i * 16 + r;
        af[i] = *(const short8*)(sA + (((ra << 7) + (kk << 6) + (g << 4)) ^ ((ra & 7) << 4)));
      }
#pragma unroll
      for (int j = 0; j < 2; ++j) {
        int rb = wn + j * 16 + r;
        bfr[j] = *(const short8*)(sB + (((rb << 7) + (kk << 6) + (g << 4)) ^ ((rb & 7) << 4)));
      }
#pragma unroll
      for (int i = 0; i < 4; ++i)
#pragma unroll
        for (int j = 0; j < 2; ++j) acc[i][j] = mfma16(af[i], bfr[j], acc[i][j]);
    }
    __syncthreads();
  }
#pragma unroll
  for (int i = 0; i < 4; ++i)
#pragma unroll
    for (int j = 0; j < 2; ++j)
#pragma unroll
      for (int jj = 0; jj < 4; ++jj) {
        int row = m0 + wm + i * 16 + g * 4 + jj;
        int col = n0 + wn + j * 16 + r;
        C[(size_t)row * N + col] = acc[i][j][jj];
      }
}

// ---------------- fused RoPE(Q,K) (vectorized) + V-transpose ----------------
// Q scaled by 0.125*log2e: downstream softmax works in exp2 domain.
__global__ __launch_bounds__(256) void rope_tv(const unsigned short* __restrict__ cf,
                                               unsigned short* __restrict__ qb,
                                               unsigned short* __restrict__ kb,
                                               unsigned short* __restrict__ vt) {
  __shared__ unsigned short tile[64][72];
  const int bid = blockIdx.x;
  if (bid < 2048) {
    int i = bid * 256 + threadIdx.x;  // 512K threads: ((b*1024+s)*16+h)*8+t8
    int t8 = i & 7, h = (i >> 3) & 15, s = (i >> 7) & 1023, b = i >> 17;
    const unsigned short* src = cf + (size_t)(b * SEQ + s) * N3 + h * DKH + t8 * 8;
    short8 q8 = *(const short8*)src;
    short8 k8 = *(const short8*)(src + DM);
    uint4v qo, ko;
    const float qs = 0.125f * LOG2E;
#pragma unroll
    for (int p = 0; p < 4; ++p) {
      int kidx = t8 * 4 + p;
      float freq = __expf(-(float)kidx * 0.28782313662425572f);  // 10000^(-k/32)
      float sn, cs;
      __sincosf((float)s * freq, &sn, &cs);
      float qe = bf2f((unsigned short)q8[2 * p]), qv = bf2f((unsigned short)q8[2 * p + 1]);
      float ke = bf2f((unsigned short)k8[2 * p]), kv = bf2f((unsigned short)k8[2 * p + 1]);
      qo[p] = cvt_pk_bf16((qe * cs - qv * sn) * qs, (qe * sn + qv * cs) * qs);
      ko[p] = cvt_pk_bf16(ke * cs - kv * sn, ke * sn + kv * cs);
    }
    size_t dsto = (size_t)((b * NH + h) * SEQ + s) * DKH + t8 * 8;
    *(uint4v*)(qb + dsto) = qo;
    *(uint4v*)(kb + dsto) = ko;
  } else {
    int t = bid - 2048;
    int bh = t >> 4, b = bh >> 4, h = bh & 15, s0 = (t & 15) * 64;
    int tt = threadIdx.x, row = tt >> 2, c0 = (tt & 3) * 16;
    const unsigned short* src = cf + (size_t)(b * SEQ + s0 + row) * N3 + 2 * DM + h * DKH + c0;
    short8 v0 = *(const short8*)src;
    short8 v1 = *(const short8*)(src + 8);
    *(short8*)&tile[row][c0] = v0;
    *(short8*)&tile[row][c0 + 8] = v1;
    __syncthreads();
    unsigned short* dst = vt + ((size_t)bh * DKH + row) * SEQ + s0 + c0;
    short8 o0, o1;
#pragma unroll
    for (int j = 0; j < 8; ++j) o0[j] = (short)tile[c0 + j][row];
#pragma unroll
    for (int j = 0; j < 8; ++j) o1[j] = (short)tile[c0 + 8 + j][row];
    *(short8*)dst = o0;
    *(short8*)(dst + 8) = o1;
  }
}

// ---------------- causal flash attention (v8 + T5 setprio) ----------------------
// grid (8, 64), 512 threads. Block bx handles q-tiles qhi=15-bx AND qlo=bx.
// Waves 0-3 own the hi tile's 16-row slices; waves 4-7 the lo tile. 16 waves/CU
// at different phases -> setprio(1) around MFMA clusters lets the CU scheduler
// favor matrix-issuing waves (T5: +4-7% measured on attn with phase diversity).
__global__ __launch_bounds__(512) void attn_kernel(const unsigned short* __restrict__ qb,
                                                   const unsigned short* __restrict__ kb,
                                                   const unsigned short* __restrict__ vt,
                                                   unsigned short* __restrict__ ob) {
  __shared__ char kl[2][8192];
  __shared__ char vl[2][8192];
  __shared__ unsigned short plds[8][1024];  // per-wave P buffer
  const int bx = blockIdx.x, bh = blockIdx.y, b = bh >> 4, h = bh & 15;
  const int tid = threadIdx.x, w = tid >> 6, lane = tid & 63;
  const int g = lane >> 4, r = lane & 15;
  const float DEFER = 8.f * LOG2E;
  const int qblk = (w < 4) ? (15 - bx) : bx;  // hi tile for waves 0-3, lo for 4-7
  const int nkt = qblk + 1;                   // K-tiles this wave computes
  const int NKT = 16 - bx;                    // K-tiles the block stages (hi span)
  const unsigned short* Q = qb + (size_t)bh * SEQ * DKH;
  const char* Kp = (const char*)(kb + (size_t)bh * SEQ * DKH);
  const char* Vp = (const char*)(vt + (size_t)bh * DKH * SEQ);

  const int p0 = tid * 16;
  const int o0 = p0 ^ (((p0 >> 7) & 7) << 4);  // inverse-swizzled logical pos
  const size_t ks0 = (size_t)(o0 >> 7) * 128 + (o0 & 127);
  const size_t vs0 = (size_t)(o0 >> 7) * 2048 + (o0 & 127);

#define STAGE_KV(bi, kt)                                                          \
  do {                                                                            \
    const char* kbase = Kp + (size_t)(kt) * 8192;                                 \
    const char* vbase = Vp + (size_t)(kt) * 128;                                  \
    __builtin_amdgcn_global_load_lds((const AS1 void*)(kbase + ks0),              \
                                     (AS3 void*)(kl[bi] + p0), 16, 0, 0);         \
    __builtin_amdgcn_global_load_lds((const AS1 void*)(vbase + vs0),              \
                                     (AS3 void*)(vl[bi] + p0), 16, 0, 0);         \
  } while (0)

  short8 qf0, qf1;
  {
    int qrow = qblk * 64 + (w & 3) * 16 + r;
    qf0 = *(const short8*)(Q + (size_t)qrow * DKH + g * 8);
    qf1 = *(const short8*)(Q + (size_t)qrow * DKH + 32 + g * 8);
  }
  f32x4 oacc[4] = {};
  float mrun = -1e30f, lrun = 0.f;
  const int qg = qblk * 64 + (w & 3) * 16 + r;  // this lane's q-row (global)
  char* pbase = (char*)&plds[w][0];

  STAGE_KV(0, 0);
  __syncthreads();

  for (int kt = 0; kt < NKT; ++kt) {
    if (kt + 1 < NKT) STAGE_KV((kt + 1) & 1, kt + 1);  // prefetch next tile
    if (kt < nkt) {  // wave-uniform: lo-waves skip compute past their span
      const char* kb_ = kl[kt & 1];
      const char* vb_ = vl[kt & 1];
      f32x4 sh[4] = {};
      __builtin_amdgcn_s_setprio(1);
#pragma unroll
      for (int nb = 0; nb < 4; ++nb) {
        int ra = nb * 16 + r;
        short8 kf0 = *(const short8*)(kb_ + ((ra * 128 + g * 16) ^ ((ra & 7) << 4)));
        short8 kf1 = *(const short8*)(kb_ + ((ra * 128 + 64 + g * 16) ^ ((ra & 7) << 4)));
        sh[nb] = mfma16(kf0, qf0, sh[nb]);  // swapped: S[k][q]
        sh[nb] = mfma16(kf1, qf1, sh[nb]);
      }
      __builtin_amdgcn_s_setprio(0);
      if (kt == nkt - 1) {  // diagonal: mask k > q (per-lane q)
#pragma unroll
        for (int nb = 0; nb < 4; ++nb)
#pragma unroll
          for (int j = 0; j < 4; ++j)
            if (kt * 64 + nb * 16 + g * 4 + j > qg) sh[nb][j] = -1e30f;
      }
      // ---- per-lane softmax (defer-max, exp2 domain) ----
      {
        float a0 = fmaxf(fmaxf(sh[0][0], sh[0][1]), fmaxf(sh[0][2], sh[0][3]));
        float a1 = fmaxf(fmaxf(sh[1][0], sh[1][1]), fmaxf(sh[1][2], sh[1][3]));
        float a2 = fmaxf(fmaxf(sh[2][0], sh[2][1]), fmaxf(sh[2][2], sh[2][3]));
        float a3 = fmaxf(fmaxf(sh[3][0], sh[3][1]), fmaxf(sh[3][2], sh[3][3]));
        float tm = fmaxf(fmaxf(a0, a1), fmaxf(a2, a3));
        tm = fmaxf(tm, __shfl_xor(tm, 16, 64));
        tm = fmaxf(tm, __shfl_xor(tm, 32, 64));
        if (!__all(tm <= mrun + DEFER)) {
          float mnew = fmaxf(mrun, tm);
          float scl = exp2f(mrun - mnew);
          mrun = mnew;
          lrun *= scl;
#pragma unroll
          for (int db = 0; db < 4; ++db) {
            f32x4 t = oacc[db];
            t[0] *= scl; t[1] *= scl; t[2] *= scl; t[3] *= scl;
            oacc[db] = t;
          }
        }
        float ps = 0.f;
#pragma unroll
        for (int nb = 0; nb < 4; ++nb)
#pragma unroll
          for (int j = 0; j < 4; ++j) {
            float p = exp2f(sh[nb][j] - mrun);
            sh[nb][j] = p;
            ps += p;
          }
        ps += __shfl_xor(ps, 16, 64);
        ps += __shfl_xor(ps, 32, 64);
        lrun += ps;
#pragma unroll
        for (int nb = 0; nb < 4; ++nb) {
          uint2v pk;
          pk.x = cvt_pk_bf16(sh[nb][0], sh[nb][1]);
          pk.y = cvt_pk_bf16(sh[nb][2], sh[nb][3]);
          *(uint2v*)(pbase + ((r * 128 + nb * 32 + g * 8) ^ ((r & 7) << 4))) = pk;
        }
      }
      // P write -> read is same-wave only
      asm volatile("s_waitcnt lgkmcnt(0)" ::: "memory");
      __builtin_amdgcn_sched_barrier(0);
      short8 pf0 = *(const short8*)(pbase + ((r * 128 + g * 16) ^ ((r & 7) << 4)));
      short8 pf1 = *(const short8*)(pbase + ((r * 128 + 64 + g * 16) ^ ((r & 7) << 4)));
      __builtin_amdgcn_s_setprio(1);
#pragma unroll
      for (int db = 0; db < 4; ++db) {
        int rv = db * 16 + r;
        short8 vf0 = *(const short8*)(vb_ + ((rv * 128 + g * 16) ^ ((rv & 7) << 4)));
        short8 vf1 = *(const short8*)(vb_ + ((rv * 128 + 64 + g * 16) ^ ((rv & 7) << 4)));
        oacc[db] = mfma16(vf0, pf0, oacc[db]);  // swapped: O[d][q]
        oacc[db] = mfma16(vf1, pf1, oacc[db]);
      }
      __builtin_amdgcn_s_setprio(0);
    }
    __syncthreads();  // staging drained + all waves done with buffers
  }
  // epilogue: lane holds O[d=db*16+g*4+j][q=own row]; pack 4 bf16 -> 8B stores
  {
    float inv = 1.f / lrun;
    unsigned short* orow = ob + (size_t)(b * SEQ + qg) * DM + h * DKH;
#pragma unroll
    for (int db = 0; db < 4; ++db) {
      uint2v pk;
      pk.x = cvt_pk_bf16(oacc[db][0] * inv, oacc[db][1] * inv);
      pk.y = cvt_pk_bf16(oacc[db][2] * inv, oacc[db][3] * inv);
      *(uint2v*)(orow + db * 16 + g * 4) = pk;
    }
  }
#undef STAGE_KV
}

extern "C" void kernel_launch(void* const* d_in, const int* in_sizes, int n_in,
                              void* d_out, int out_size, void* d_ws, size_t ws_size,
                              hipStream_t stream) {
  const float* x = (const float*)d_in[0];
  // d_in[1] = token_positions (reference ignores it; positions == arange(S))
  const float* wq = (const float*)d_in[2];
  const float* wk = (const float*)d_in[3];
  const float* wv = (const float*)d_in[4];
  const float* wo = (const float*)d_in[5];
  char* ws = (char*)d_ws;
  unsigned short* xb = (unsigned short*)(ws);                  // 8 MiB
  unsigned short* wqkv = (unsigned short*)(ws + (8u << 20));   // 6 MiB [Wq;Wk;Wv][3072][1024]
  unsigned short* wob = (unsigned short*)(ws + (14u << 20));   // 2 MiB
  unsigned short* cf = (unsigned short*)(ws + (16u << 20));    // 24 MiB QKV gemm out (b,s,3072)
  unsigned short* qbuf = (unsigned short*)(ws + (40u << 20));  // 8 MiB (bh,s,d)
  unsigned short* kbuf = (unsigned short*)(ws + (48u << 20));  // 8 MiB (bh,s,d)
  unsigned short* vtb = (unsigned short*)(ws + (56u << 20));   // 8 MiB (bh,d,s)
  unsigned short* obuf = (unsigned short*)(ws + (64u << 20));  // 8 MiB (b,s,e)
  float* out = (float*)d_out;

  convert_kernel<<<8192, 256, 0, stream>>>(x, wq, wk, wv, wo, xb, wqkv, wob);
  gemm_bt<unsigned short><<<dim3(24, 32), 256, 0, stream>>>(xb, wqkv, cf, MROWS, N3, DM);
  rope_tv<<<3072, 256, 0, stream>>>(cf, qbuf, kbuf, vtb);
  attn_kernel<<<dim3(8, 64), 512, 0, stream>>>(qbuf, kbuf, vtb, obuf);
  gemm_n64<<<dim3(16, 32), 256, 0, stream>>>(obuf, wob, out, MROWS, DM, DM);
}